// Round 8
// baseline (1201.634 us; speedup 1.0000x reference)
//
#include <hip/hip_runtime.h>
#include <hip/hip_bf16.h>
#include <string.h>

#define M_NODES 100000
#define K_FEAT 512
#define N_OUT_C 64
#define N_EDGES_C 1600000

// ---- bucketed counting-scatter geometry -----------------------------------
#define BKT_NODES 32                         // nodes per bucket (dst>>5)
#define NB (M_NODES / BKT_NODES)             // 3125 buckets
#define NSUB 8                               // per-XCD sub-lists (bid & 7)
#define SUBCAP 160                           // per-sub mean 64; 160 = huge margin
#define OVCAP 8192                           // overflow entries (expected 0 used)

#define SC_EPT 8
#define SC_BLOCKS ((N_EDGES_C / SC_EPT + 255) / 256)   // 782

// MEASUREMENT ROUND 2: all three hot kernels run 8x so each surfaces in the
// rocprof top-5 with full counters. fill reps 1..7 replay into scratch
// (cnt regions 1..7 + bkt2) -- real output bit-identical. Revert next round.
#define GEMM_REPS 8
#define AGG_REPS 8
#define FILL_REPS 8

typedef __attribute__((ext_vector_type(8))) short short8;
typedef __attribute__((ext_vector_type(4))) float floatx4;

// fp32 -> bf16 round-to-nearest-even (scalar; used in cold paths)
static __device__ __forceinline__ unsigned short f2bf(float f) {
    unsigned int u = __float_as_uint(f);
    u += 0x7fffu + ((u >> 16) & 1u);
    return (unsigned short)(u >> 16);
}
static __device__ __forceinline__ float bf2f(unsigned short u) {
    return __uint_as_float((unsigned int)u << 16);
}
// packed pair convert: (lo,hi) -> one u32 of 2x bf16 via v_cvt_pk_bf16_f32
static __device__ __forceinline__ unsigned int cvt_pk_bf16(float lo, float hi) {
    __hip_bfloat162 h2 = __float22bfloat162_rn(make_float2(lo, hi));
    unsigned int u;
    memcpy(&u, &h2, sizeof(u));
    return u;
}

// ---------------------------------------------------------------------------
// conv_w_zero: W convert + zero ALL 8 cnt regions (real + 7 scratch) + ov_cnt.
// ---------------------------------------------------------------------------
__global__ __launch_bounds__(256) void conv_w_zero(const float* __restrict__ W,
                                                   unsigned short* __restrict__ Wb,
                                                   int* __restrict__ cnt,
                                                   int* __restrict__ ov_cnt) {
    int id = blockIdx.x * 256 + threadIdx.x;
    for (int i = id; i < NB * NSUB * FILL_REPS; i += 32768) cnt[i] = 0;
    if (id == 0) *ov_cnt = 0;
    if (id < K_FEAT * N_OUT_C) {
        int k = id >> 6;
        int n = id & 63;
        Wb[((size_t)(k >> 3) * 64 + n) * 8 + (k & 7)] = f2bf(W[(size_t)k * 64 + n]);
    }
}

// ---------------------------------------------------------------------------
// MFMA GEMM: h[M,64] = x[M,512] @ W[512,64]. (GEMM_REPS for measurement.)
// ---------------------------------------------------------------------------
__global__ __launch_bounds__(256) void gemm_mfma(const float* __restrict__ x,
                                                 const unsigned short* __restrict__ Wb,
                                                 unsigned short* __restrict__ hb) {
    const int wid  = (blockIdx.x * 256 + (int)threadIdx.x) >> 6;
    const int lane = threadIdx.x & 63;
    if (wid >= M_NODES / 16) return;

    const int m    = lane & 15;
    const int quad = lane >> 4;
    const int rowBase = wid * 16;
    const float* aRow = x + (size_t)(rowBase + m) * K_FEAT + quad * 8;

    #pragma unroll 1
    for (int rep = 0; rep < GEMM_REPS; ++rep) {
        floatx4 acc0 = {0.f, 0.f, 0.f, 0.f};
        floatx4 acc1 = {0.f, 0.f, 0.f, 0.f};
        floatx4 acc2 = {0.f, 0.f, 0.f, 0.f};
        floatx4 acc3 = {0.f, 0.f, 0.f, 0.f};

        for (int k0 = 0; k0 < K_FEAT; k0 += 128) {
            float4 px[8];
            #pragma unroll
            for (int u = 0; u < 4; u++) {
                px[2 * u]     = *(const float4*)(aRow + k0 + u * 32);
                px[2 * u + 1] = *(const float4*)(aRow + k0 + u * 32 + 4);
            }

            #pragma unroll
            for (int u = 0; u < 4; u++) {
                const int kk = k0 + u * 32;
                union { short8 s; unsigned int uu[4]; } av;
                av.uu[0] = cvt_pk_bf16(px[2 * u].x,     px[2 * u].y);
                av.uu[1] = cvt_pk_bf16(px[2 * u].z,     px[2 * u].w);
                av.uu[2] = cvt_pk_bf16(px[2 * u + 1].x, px[2 * u + 1].y);
                av.uu[3] = cvt_pk_bf16(px[2 * u + 1].z, px[2 * u + 1].w);
                short8 a = av.s;

                const unsigned short* wbase = Wb + (size_t)((kk >> 3) + quad) * 512 + m * 8;
                short8 b0 = *(const short8*)(wbase + 0 * 128);
                short8 b1 = *(const short8*)(wbase + 1 * 128);
                short8 b2 = *(const short8*)(wbase + 2 * 128);
                short8 b3 = *(const short8*)(wbase + 3 * 128);

                acc0 = __builtin_amdgcn_mfma_f32_16x16x32_bf16(a, b0, acc0, 0, 0, 0);
                acc1 = __builtin_amdgcn_mfma_f32_16x16x32_bf16(a, b1, acc1, 0, 0, 0);
                acc2 = __builtin_amdgcn_mfma_f32_16x16x32_bf16(a, b2, acc2, 0, 0, 0);
                acc3 = __builtin_amdgcn_mfma_f32_16x16x32_bf16(a, b3, acc3, 0, 0, 0);
            }
        }

        unsigned short* hp = hb + (size_t)(rowBase + quad * 4) * N_OUT_C + m;
        #pragma unroll
        for (int r = 0; r < 4; r++) {
            hp[(size_t)r * N_OUT_C + 0]  = f2bf(acc0[r]);
            hp[(size_t)r * N_OUT_C + 16] = f2bf(acc1[r]);
            hp[(size_t)r * N_OUT_C + 32] = f2bf(acc2[r]);
            hp[(size_t)r * N_OUT_C + 48] = f2bf(acc3[r]);
        }
    }
}

// ---------------------------------------------------------------------------
// bucket_fill: rep 0 = real scatter (identical to 437us baseline).
// Reps 1..7 = identical atomic+scatter replay into scratch cnt region + bkt2
// (fresh zeroed counters each rep; no overflow path) -- pure measurement.
// ---------------------------------------------------------------------------
__global__ __launch_bounds__(256) void bucket_fill(const int* __restrict__ esrc,
                                                   const int* __restrict__ edst,
                                                   const float* __restrict__ ew,
                                                   int* __restrict__ cnt,
                                                   int2* __restrict__ bkt,
                                                   int* __restrict__ ov_cnt,
                                                   int4* __restrict__ ov,
                                                   int2* __restrict__ bkt2) {
    int base = (blockIdx.x * 256 + threadIdx.x) * SC_EPT;
    if (base >= N_EDGES_C) return;
    const int sub = blockIdx.x & (NSUB - 1);

    int4   s0 = *(const int4*)&esrc[base];
    int4   s1 = *(const int4*)&esrc[base + 4];
    int4   d0 = *(const int4*)&edst[base];
    int4   d1 = *(const int4*)&edst[base + 4];
    float4 w0 = *(const float4*)&ew[base];
    float4 w1 = *(const float4*)&ew[base + 4];

    int dd[8] = {d0.x, d0.y, d0.z, d0.w, d1.x, d1.y, d1.z, d1.w};
    int ss[8] = {s0.x, s0.y, s0.z, s0.w, s1.x, s1.y, s1.z, s1.w};
    float wwv[8] = {w0.x, w0.y, w0.z, w0.w, w1.x, w1.y, w1.z, w1.w};

    int idx[8], r[8];
    #pragma unroll
    for (int i = 0; i < 8; i++) {
        idx[i] = (dd[i] >> 5) * NSUB + sub;
        r[i] = atomicAdd(&cnt[idx[i]], 1);
    }
    #pragma unroll
    for (int i = 0; i < 8; i++) {
        if (r[i] < SUBCAP) {
            bkt[(size_t)idx[i] * SUBCAP + r[i]] =
                make_int2(ss[i] | ((dd[i] & 31) << 17), __float_as_int(wwv[i]));
        } else {
            int k = atomicAdd(ov_cnt, 1);
            if (k < OVCAP) ov[k] = make_int4(dd[i], ss[i], __float_as_int(wwv[i]), 0);
        }
    }

    // scratch replays (measurement only)
    #pragma unroll 1
    for (int rep = 1; rep < FILL_REPS; ++rep) {
        int* c2 = cnt + (size_t)rep * (NB * NSUB);
        #pragma unroll
        for (int i = 0; i < 8; i++) {
            int r2 = atomicAdd(&c2[idx[i]], 1);
            if (r2 < SUBCAP)
                bkt2[(size_t)idx[i] * SUBCAP + r2] =
                    make_int2(ss[i] | ((dd[i] & 31) << 17), __float_as_int(wwv[i]));
        }
    }
}

// ---------------------------------------------------------------------------
// bucket_agg: LDS counting sort + register gather + softmax. (AGG_REPS=8.)
// ---------------------------------------------------------------------------
#define AGG_MAXE (NSUB * SUBCAP)   // 1280

__global__ __launch_bounds__(256) void bucket_agg(const int* __restrict__ cnt,
                                                  const int2* __restrict__ bkt,
                                                  const unsigned short* __restrict__ hb,
                                                  const int* __restrict__ ov_cnt,
                                                  const int4* __restrict__ ov,
                                                  float* __restrict__ out) {
    __shared__ int2 ebuf[AGG_MAXE];     // 10.25 KB
    __shared__ int2 sorted[AGG_MAXE];   // 10.25 KB
    __shared__ int  hist[32];
    __shared__ int  startS[33];
    __shared__ int  cursor[32];
    __shared__ int  subcnt[NSUB];

    const int b = blockIdx.x;
    const int t = threadIdx.x;

    #pragma unroll 1
    for (int rep = 0; rep < AGG_REPS; ++rep) {
        __syncthreads();   // quiesce previous rep before re-initializing LDS

        if (t < NSUB) subcnt[t] = min(cnt[b * NSUB + t], SUBCAP);
        if (t < 32) hist[t] = 0;
        __syncthreads();

        int pre[NSUB + 1];
        pre[0] = 0;
        #pragma unroll
        for (int s = 0; s < NSUB; s++) pre[s + 1] = pre[s] + subcnt[s];
        const int total = pre[NSUB];

        #pragma unroll
        for (int s = 0; s < NSUB; s++) {
            int c = subcnt[s];
            const int2* g = bkt + (size_t)(b * NSUB + s) * SUBCAP;
            for (int i = t; i < c; i += 256) ebuf[pre[s] + i] = g[i];
        }
        __syncthreads();

        for (int i = t; i < total; i += 256) atomicAdd(&hist[ebuf[i].x >> 17], 1);
        __syncthreads();

        if (t == 0) {
            int s = 0;
            #pragma unroll
            for (int i = 0; i < 32; i++) { startS[i] = s; s += hist[i]; }
            startS[32] = s;
        }
        __syncthreads();
        if (t < 32) cursor[t] = startS[t];
        __syncthreads();

        for (int i = t; i < total; i += 256) {
            int2 e = ebuf[i];
            int p = atomicAdd(&cursor[e.x >> 17], 1);
            sorted[p] = e;
        }
        __syncthreads();

        const int group = t >> 4;          // 16 groups, each handles 2 nodes
        const int c4    = t & 15;          // channels [c4*4, c4*4+4)
        const int ovn   = min(*ov_cnt, OVCAP);

        for (int ln = group; ln < 32; ln += 16) {
            const int s0 = startS[ln];
            const int e0 = startS[ln + 1];
            float4 acc = make_float4(0.f, 0.f, 0.f, 0.f);

            int r = s0;
            for (; r + 4 <= e0; r += 4) {
                int2 q0 = sorted[r + 0];
                int2 q1 = sorted[r + 1];
                int2 q2 = sorted[r + 2];
                int2 q3 = sorted[r + 3];
                ushort4 v0 = *(const ushort4*)&hb[(size_t)(q0.x & 0x1FFFF) * N_OUT_C + c4 * 4];
                ushort4 v1 = *(const ushort4*)&hb[(size_t)(q1.x & 0x1FFFF) * N_OUT_C + c4 * 4];
                ushort4 v2 = *(const ushort4*)&hb[(size_t)(q2.x & 0x1FFFF) * N_OUT_C + c4 * 4];
                ushort4 v3 = *(const ushort4*)&hb[(size_t)(q3.x & 0x1FFFF) * N_OUT_C + c4 * 4];
                float w0 = __int_as_float(q0.y);
                float w1 = __int_as_float(q1.y);
                float w2 = __int_as_float(q2.y);
                float w3 = __int_as_float(q3.y);
                acc.x += w0 * bf2f(v0.x) + w1 * bf2f(v1.x) + w2 * bf2f(v2.x) + w3 * bf2f(v3.x);
                acc.y += w0 * bf2f(v0.y) + w1 * bf2f(v1.y) + w2 * bf2f(v2.y) + w3 * bf2f(v3.y);
                acc.z += w0 * bf2f(v0.z) + w1 * bf2f(v1.z) + w2 * bf2f(v2.z) + w3 * bf2f(v3.z);
                acc.w += w0 * bf2f(v0.w) + w1 * bf2f(v1.w) + w2 * bf2f(v2.w) + w3 * bf2f(v3.w);
            }
            for (; r < e0; r++) {
                int2 q = sorted[r];
                ushort4 v = *(const ushort4*)&hb[(size_t)(q.x & 0x1FFFF) * N_OUT_C + c4 * 4];
                float w = __int_as_float(q.y);
                acc.x += w * bf2f(v.x);
                acc.y += w * bf2f(v.y);
                acc.z += w * bf2f(v.z);
                acc.w += w * bf2f(v.w);
            }

            const int node = b * BKT_NODES + ln;
            if (ovn) {                      // ~never taken; correctness net
                for (int k = 0; k < ovn; k++) {
                    int4 o = ov[k];
                    if (o.x == node) {
                        ushort4 v = *(const ushort4*)&hb[(size_t)o.y * N_OUT_C + c4 * 4];
                        float w = __int_as_float(o.z);
                        acc.x += w * bf2f(v.x);
                        acc.y += w * bf2f(v.y);
                        acc.z += w * bf2f(v.z);
                        acc.w += w * bf2f(v.w);
                    }
                }
            }

            // softmax over 64 channels = 16 lanes x 4
            float m = fmaxf(fmaxf(acc.x, acc.y), fmaxf(acc.z, acc.w));
            #pragma unroll
            for (int off = 1; off < 16; off <<= 1)
                m = fmaxf(m, __shfl_xor(m, off));

            float4 ev;
            ev.x = __expf(acc.x - m);
            ev.y = __expf(acc.y - m);
            ev.z = __expf(acc.z - m);
            ev.w = __expf(acc.w - m);

            float sum = ev.x + ev.y + ev.z + ev.w;
            #pragma unroll
            for (int off = 1; off < 16; off <<= 1)
                sum += __shfl_xor(sum, off);

            float inv = 1.0f / sum;
            *(float4*)&out[(size_t)node * N_OUT_C + c4 * 4] =
                make_float4(ev.x * inv, ev.y * inv, ev.z * inv, ev.w * inv);
        }
    }
}

// ---------------------------------------------------------------------------
// Fallback path (ws too small): fp32 GEMM + atomic scatter + softmax
// ---------------------------------------------------------------------------
__global__ __launch_bounds__(256) void gemm_xw(const float* __restrict__ x,
                                               const float* __restrict__ W,
                                               float* __restrict__ h) {
    __shared__ float As[64][33];
    __shared__ float Bs[32][64];
    const int t  = threadIdx.x;
    const int tx = t & 15;
    const int ty = t >> 4;
    const int rowBase = blockIdx.x * 64;
    float acc[4][4] = {{0.f}};
    for (int k0 = 0; k0 < K_FEAT; k0 += 32) {
        #pragma unroll
        for (int i = 0; i < 2; i++) {
            int f = t + i * 256;
            int r = f >> 3, c4 = f & 7;
            int grow = rowBase + r;
            float4 v = make_float4(0.f, 0.f, 0.f, 0.f);
            if (grow < M_NODES)
                v = *(const float4*)&x[(size_t)grow * K_FEAT + k0 + c4 * 4];
            As[r][c4 * 4 + 0] = v.x; As[r][c4 * 4 + 1] = v.y;
            As[r][c4 * 4 + 2] = v.z; As[r][c4 * 4 + 3] = v.w;
        }
        #pragma unroll
        for (int i = 0; i < 2; i++) {
            int f = t + i * 256;
            ((float4*)Bs)[f] = ((const float4*)(W + (size_t)k0 * N_OUT_C))[f];
        }
        __syncthreads();
        #pragma unroll
        for (int k = 0; k < 32; k++) {
            float a0 = As[ty * 4 + 0][k], a1 = As[ty * 4 + 1][k];
            float a2 = As[ty * 4 + 2][k], a3 = As[ty * 4 + 3][k];
            float4 b = *(float4*)&Bs[k][tx * 4];
            acc[0][0] += a0 * b.x; acc[0][1] += a0 * b.y; acc[0][2] += a0 * b.z; acc[0][3] += a0 * b.w;
            acc[1][0] += a1 * b.x; acc[1][1] += a1 * b.y; acc[1][2] += a1 * b.z; acc[1][3] += a1 * b.w;
            acc[2][0] += a2 * b.x; acc[2][1] += a2 * b.y; acc[2][2] += a2 * b.z; acc[2][3] += a2 * b.w;
            acc[3][0] += a3 * b.x; acc[3][1] += a3 * b.y; acc[3][2] += a3 * b.z; acc[3][3] += a3 * b.w;
        }
        __syncthreads();
    }
    #pragma unroll
    for (int i = 0; i < 4; i++) {
        int row = rowBase + ty * 4 + i;
        if (row < M_NODES)
            *(float4*)&h[(size_t)row * N_OUT_C + tx * 4] =
                make_float4(acc[i][0], acc[i][1], acc[i][2], acc[i][3]);
    }
}

__global__ __launch_bounds__(256) void scatter_edges(const int* __restrict__ esrc,
                                                     const int* __restrict__ edst,
                                                     const float* __restrict__ ew,
                                                     const float* __restrict__ h,
                                                     float* __restrict__ agg) {
    int tid = blockIdx.x * 256 + threadIdx.x;
    int e = tid >> 4;
    int g = tid & 15;
    if (e >= N_EDGES_C) return;
    int s = esrc[e], d = edst[e];
    float w = ew[e];
    float4 v = *(const float4*)&h[(size_t)s * N_OUT_C + g * 4];
    float* p = agg + (size_t)d * N_OUT_C + g * 4;
    unsafeAtomicAdd(p + 0, v.x * w);
    unsafeAtomicAdd(p + 1, v.y * w);
    unsafeAtomicAdd(p + 2, v.z * w);
    unsafeAtomicAdd(p + 3, v.w * w);
}

__global__ __launch_bounds__(256) void softmax_rows(float* __restrict__ out) {
    int wave = (blockIdx.x * 256 + threadIdx.x) >> 6;
    int lane = threadIdx.x & 63;
    if (wave >= M_NODES) return;
    size_t idx = (size_t)wave * N_OUT_C + lane;
    float v = out[idx];
    float m = v;
    #pragma unroll
    for (int off = 32; off > 0; off >>= 1) m = fmaxf(m, __shfl_xor(m, off));
    float ev = __expf(v - m);
    float sum = ev;
    #pragma unroll
    for (int off = 32; off > 0; off >>= 1) sum += __shfl_xor(sum, off);
    out[idx] = ev / sum;
}

// ---------------------------------------------------------------------------
extern "C" void kernel_launch(void* const* d_in, const int* in_sizes, int n_in,
                              void* d_out, int out_size, void* d_ws, size_t ws_size,
                              hipStream_t stream) {
    const float* x    = (const float*)d_in[0];
    const int*   esrc = (const int*)d_in[1];
    const int*   edst = (const int*)d_in[2];
    const float* ew   = (const float*)d_in[3];
    const float* W    = (const float*)d_in[4];
    float* out = (float*)d_out;

    char* ws = (char*)d_ws;
    size_t off_hb   = 0;
    size_t sz_hb    = (size_t)M_NODES * N_OUT_C * sizeof(unsigned short);     // 12.8 MB
    size_t off_cnt  = (off_hb + sz_hb + 15) & ~15ull;
    size_t sz_cnt   = (size_t)NB * NSUB * FILL_REPS * sizeof(int);            // 800 KB (real + 7 scratch)
    size_t off_bkt  = (off_cnt + sz_cnt + 15) & ~15ull;
    size_t sz_bkt   = (size_t)NB * NSUB * SUBCAP * sizeof(int2);              // 32 MB
    size_t off_bkt2 = (off_bkt + sz_bkt + 15) & ~15ull;
    size_t sz_bkt2  = sz_bkt;                                                 // 32 MB scratch
    size_t off_wb   = (off_bkt2 + sz_bkt2 + 15) & ~15ull;
    size_t sz_wb    = (size_t)K_FEAT * N_OUT_C * sizeof(unsigned short);      // 64 KB
    size_t off_ovc  = (off_wb + sz_wb + 15) & ~15ull;
    size_t sz_ovc   = 16;
    size_t off_ov   = (off_ovc + sz_ovc + 15) & ~15ull;
    size_t sz_ov    = (size_t)OVCAP * sizeof(int4);                           // 128 KB
    size_t needed   = off_ov + sz_ov;                                         // ~78 MB

    if (ws_size >= needed) {
        unsigned short* hb = (unsigned short*)(ws + off_hb);
        int*  cnt    = (int*)(ws + off_cnt);
        int2* bkt    = (int2*)(ws + off_bkt);
        int2* bkt2   = (int2*)(ws + off_bkt2);
        unsigned short* Wb = (unsigned short*)(ws + off_wb);
        int*  ov_cnt = (int*)(ws + off_ovc);
        int4* ov     = (int4*)(ws + off_ov);

        conv_w_zero<<<128, 256, 0, stream>>>(W, Wb, cnt, ov_cnt);
        gemm_mfma<<<(M_NODES / 16 + 3) / 4, 256, 0, stream>>>(x, Wb, hb);
        bucket_fill<<<SC_BLOCKS, 256, 0, stream>>>(esrc, edst, ew, cnt, bkt, ov_cnt, ov, bkt2);
        bucket_agg<<<NB, 256, 0, stream>>>(cnt, bkt, hb, ov_cnt, ov, out);
    } else {
        // fallback: fp32 gemm + atomic scatter
        float* h = (float*)ws;
        hipMemsetAsync(d_out, 0, (size_t)M_NODES * N_OUT_C * sizeof(float), stream);
        gemm_xw<<<(M_NODES + 63) / 64, 256, 0, stream>>>(x, W, h);
        scatter_edges<<<(N_EDGES_C * 16 + 255) / 256, 256, 0, stream>>>(esrc, edst, ew, h, out);
        softmax_rows<<<(M_NODES + 3) / 4, 256, 0, stream>>>(out);
    }
}

// Round 9
// 389.248 us; speedup vs baseline: 3.0871x; 3.0871x over previous
//
#include <hip/hip_runtime.h>
#include <hip/hip_bf16.h>
#include <string.h>

#define M_NODES 100000
#define K_FEAT 512
#define N_OUT_C 64
#define N_EDGES_C 1600000

// ---- two-phase partition geometry -----------------------------------------
#define NBIN 98                       // coarse bins: dst>>10 (1024 nodes/bin)
#define BINCAP 18432                  // mean 16384, +16 sigma
#define BKT_NODES 32                  // fine buckets: dst>>5
#define NB (M_NODES / BKT_NODES)      // 3125 buckets
#define BKCAP 768                     // mean 512, +11 sigma
#define OVCAP 8192                    // overflow net (expected 0 used)

#define PA_EPT 16
#define PA_TILE 4096                  // 256 threads * 16 edges
#define PA_BLOCKS ((N_EDGES_C + PA_TILE - 1) / PA_TILE)   // 391

typedef __attribute__((ext_vector_type(8))) short short8;
typedef __attribute__((ext_vector_type(4))) float floatx4;

// fp32 -> bf16 round-to-nearest-even
static __device__ __forceinline__ unsigned short f2bf(float f) {
    unsigned int u = __float_as_uint(f);
    u += 0x7fffu + ((u >> 16) & 1u);
    return (unsigned short)(u >> 16);
}
static __device__ __forceinline__ float bf2f(unsigned short u) {
    return __uint_as_float((unsigned int)u << 16);
}
static __device__ __forceinline__ unsigned int cvt_pk_bf16(float lo, float hi) {
    __hip_bfloat162 h2 = __float22bfloat162_rn(make_float2(lo, hi));
    unsigned int u;
    memcpy(&u, &h2, sizeof(u));
    return u;
}

// ---------------------------------------------------------------------------
// conv_w_zero: W[512][64] fp32 -> Wb bf16 frag-swizzled; zero bin cursors.
// ---------------------------------------------------------------------------
__global__ __launch_bounds__(256) void conv_w_zero(const float* __restrict__ W,
                                                   unsigned short* __restrict__ Wb,
                                                   int* __restrict__ bin_cnt,
                                                   int* __restrict__ ov_cnt) {
    int id = blockIdx.x * 256 + threadIdx.x;
    if (id < NBIN) bin_cnt[id] = 0;
    if (id == 0) *ov_cnt = 0;
    if (id < K_FEAT * N_OUT_C) {
        int k = id >> 6;
        int n = id & 63;
        Wb[((size_t)(k >> 3) * 64 + n) * 8 + (k & 7)] = f2bf(W[(size_t)k * 64 + n]);
    }
}

// ---------------------------------------------------------------------------
// MFMA GEMM: h[M,64] = x[M,512] @ W[512,64]. (Verified; single rep.)
// ---------------------------------------------------------------------------
__global__ __launch_bounds__(256) void gemm_mfma(const float* __restrict__ x,
                                                 const unsigned short* __restrict__ Wb,
                                                 unsigned short* __restrict__ hb) {
    const int wid  = (blockIdx.x * 256 + (int)threadIdx.x) >> 6;
    const int lane = threadIdx.x & 63;
    if (wid >= M_NODES / 16) return;

    const int m    = lane & 15;
    const int quad = lane >> 4;
    const int rowBase = wid * 16;
    const float* aRow = x + (size_t)(rowBase + m) * K_FEAT + quad * 8;

    floatx4 acc0 = {0.f, 0.f, 0.f, 0.f};
    floatx4 acc1 = {0.f, 0.f, 0.f, 0.f};
    floatx4 acc2 = {0.f, 0.f, 0.f, 0.f};
    floatx4 acc3 = {0.f, 0.f, 0.f, 0.f};

    for (int k0 = 0; k0 < K_FEAT; k0 += 128) {
        float4 px[8];
        #pragma unroll
        for (int u = 0; u < 4; u++) {
            px[2 * u]     = *(const float4*)(aRow + k0 + u * 32);
            px[2 * u + 1] = *(const float4*)(aRow + k0 + u * 32 + 4);
        }
        #pragma unroll
        for (int u = 0; u < 4; u++) {
            const int kk = k0 + u * 32;
            union { short8 s; unsigned int uu[4]; } av;
            av.uu[0] = cvt_pk_bf16(px[2 * u].x,     px[2 * u].y);
            av.uu[1] = cvt_pk_bf16(px[2 * u].z,     px[2 * u].w);
            av.uu[2] = cvt_pk_bf16(px[2 * u + 1].x, px[2 * u + 1].y);
            av.uu[3] = cvt_pk_bf16(px[2 * u + 1].z, px[2 * u + 1].w);
            short8 a = av.s;

            const unsigned short* wbase = Wb + (size_t)((kk >> 3) + quad) * 512 + m * 8;
            short8 b0 = *(const short8*)(wbase + 0 * 128);
            short8 b1 = *(const short8*)(wbase + 1 * 128);
            short8 b2 = *(const short8*)(wbase + 2 * 128);
            short8 b3 = *(const short8*)(wbase + 3 * 128);

            acc0 = __builtin_amdgcn_mfma_f32_16x16x32_bf16(a, b0, acc0, 0, 0, 0);
            acc1 = __builtin_amdgcn_mfma_f32_16x16x32_bf16(a, b1, acc1, 0, 0, 0);
            acc2 = __builtin_amdgcn_mfma_f32_16x16x32_bf16(a, b2, acc2, 0, 0, 0);
            acc3 = __builtin_amdgcn_mfma_f32_16x16x32_bf16(a, b3, acc3, 0, 0, 0);
        }
    }

    unsigned short* hp = hb + (size_t)(rowBase + quad * 4) * N_OUT_C + m;
    #pragma unroll
    for (int r = 0; r < 4; r++) {
        hp[(size_t)r * N_OUT_C + 0]  = f2bf(acc0[r]);
        hp[(size_t)r * N_OUT_C + 16] = f2bf(acc1[r]);
        hp[(size_t)r * N_OUT_C + 32] = f2bf(acc2[r]);
        hp[(size_t)r * N_OUT_C + 48] = f2bf(acc3[r]);
    }
}

// ---------------------------------------------------------------------------
// bin_part (phase A): partition edges into 98 coarse bins (dst>>10).
// LDS histogram -> ONE global cursor atomic per bin per block (range
// reservation) -> per-edge LDS-cursor scatter. Each block's ~42 entries/bin
// land in one ~336B burst -> lines fill while L2-resident (kills the 5.2x
// write amplification measured in R8).
// Entry: int2( src | (dst&1023)<<17 , weight_bits ).
// ---------------------------------------------------------------------------
__global__ __launch_bounds__(256) void bin_part(const int* __restrict__ esrc,
                                                const int* __restrict__ edst,
                                                const float* __restrict__ ew,
                                                int* __restrict__ bin_cnt,
                                                int2* __restrict__ binbuf,
                                                int* __restrict__ ov_cnt,
                                                int4* __restrict__ ov) {
    __shared__ int hist[NBIN];
    __shared__ int cur[NBIN];
    const int t    = threadIdx.x;
    const int tile = blockIdx.x * PA_TILE;

    int ss[PA_EPT], dd[PA_EPT];
    float wwv[PA_EPT];
    #pragma unroll
    for (int j = 0; j < PA_EPT / 4; j++) {
        int idx = tile + j * 1024 + t * 4;
        if (idx < N_EDGES_C) {
            int4   s = *(const int4*)&esrc[idx];
            int4   d = *(const int4*)&edst[idx];
            float4 w = *(const float4*)&ew[idx];
            ss[4*j+0] = s.x; ss[4*j+1] = s.y; ss[4*j+2] = s.z; ss[4*j+3] = s.w;
            dd[4*j+0] = d.x; dd[4*j+1] = d.y; dd[4*j+2] = d.z; dd[4*j+3] = d.w;
            wwv[4*j+0] = w.x; wwv[4*j+1] = w.y; wwv[4*j+2] = w.z; wwv[4*j+3] = w.w;
        } else {
            dd[4*j+0] = dd[4*j+1] = dd[4*j+2] = dd[4*j+3] = -1;
            ss[4*j+0] = ss[4*j+1] = ss[4*j+2] = ss[4*j+3] = 0;
            wwv[4*j+0] = wwv[4*j+1] = wwv[4*j+2] = wwv[4*j+3] = 0.f;
        }
    }

    if (t < NBIN) hist[t] = 0;
    __syncthreads();

    #pragma unroll
    for (int i = 0; i < PA_EPT; i++)
        if (dd[i] >= 0) atomicAdd(&hist[dd[i] >> 10], 1);
    __syncthreads();

    if (t < NBIN) cur[t] = atomicAdd(&bin_cnt[t], hist[t]);   // range reservation
    __syncthreads();

    #pragma unroll
    for (int i = 0; i < PA_EPT; i++) {
        if (dd[i] < 0) continue;
        int b = dd[i] >> 10;
        int p = atomicAdd(&cur[b], 1);                        // LDS cursor
        if (p < BINCAP) {
            binbuf[(size_t)b * BINCAP + p] =
                make_int2(ss[i] | ((dd[i] & 1023) << 17), __float_as_int(wwv[i]));
        } else {
            int k = atomicAdd(ov_cnt, 1);
            if (k < OVCAP) ov[k] = make_int4(dd[i], ss[i], __float_as_int(wwv[i]), 0);
        }
    }
}

// ---------------------------------------------------------------------------
// csr_build (phase B): one block per bin. Stream the bin's contiguous entries,
// LDS-cursor scatter into per-bucket (dst>>5) lists. All writes from one
// block into a 192KB L2-resident region -> full-line writebacks.
// Bucket entry: int2( src | (dst&31)<<17 , weight_bits )  [same as agg's fmt]
// ---------------------------------------------------------------------------
__global__ __launch_bounds__(256) void csr_build(const int* __restrict__ bin_cnt,
                                                 const int2* __restrict__ binbuf,
                                                 int* __restrict__ bkcnt,
                                                 int2* __restrict__ gbkt,
                                                 int* __restrict__ ov_cnt,
                                                 int4* __restrict__ ov) {
    __shared__ int bcur[32];
    const int bin = blockIdx.x;
    const int t   = threadIdx.x;

    if (t < 32) bcur[t] = 0;
    __syncthreads();

    const int cntb = min(bin_cnt[bin], BINCAP);
    const int2* src = binbuf + (size_t)bin * BINCAP;

    for (int i = t; i < cntb; i += 256) {
        int2 e = src[i];
        int ld = (e.x >> 17) & 1023;     // node - (bin<<10)
        int bl = ld >> 5;                // local bucket 0..31
        int p  = atomicAdd(&bcur[bl], 1);
        if (p < BKCAP) {
            gbkt[(size_t)((bin << 5) + bl) * BKCAP + p] =
                make_int2((e.x & 0x1FFFF) | ((ld & 31) << 17), e.y);
        } else {
            int k = atomicAdd(ov_cnt, 1);
            if (k < OVCAP) ov[k] = make_int4((bin << 10) + ld, e.x & 0x1FFFF, e.y, 0);
        }
    }
    __syncthreads();
    if (t < 32 && (bin << 5) + t < NB) bkcnt[(bin << 5) + t] = bcur[t];
}

// ---------------------------------------------------------------------------
// bucket_agg: one block per 32-node bucket. Load its single list, LDS
// counting-sort by local dst, register-accumulate gather + softmax.
// (Verified core from R1/R5; input simplified from 8 sub-lists to 1 list.)
// ---------------------------------------------------------------------------
__global__ __launch_bounds__(256) void bucket_agg(const int* __restrict__ bkcnt,
                                                  const int2* __restrict__ gbkt,
                                                  const unsigned short* __restrict__ hb,
                                                  const int* __restrict__ ov_cnt,
                                                  const int4* __restrict__ ov,
                                                  float* __restrict__ out) {
    __shared__ int2 ebuf[BKCAP];     // 6 KB
    __shared__ int2 sorted[BKCAP];   // 6 KB
    __shared__ int  hist[32];
    __shared__ int  startS[33];
    __shared__ int  cursor[32];

    const int b = blockIdx.x;
    const int t = threadIdx.x;

    const int total = min(bkcnt[b], BKCAP);
    if (t < 32) hist[t] = 0;
    __syncthreads();

    const int2* g = gbkt + (size_t)b * BKCAP;
    for (int i = t; i < total; i += 256) ebuf[i] = g[i];
    __syncthreads();

    for (int i = t; i < total; i += 256) atomicAdd(&hist[ebuf[i].x >> 17], 1);
    __syncthreads();

    if (t == 0) {
        int s = 0;
        #pragma unroll
        for (int i = 0; i < 32; i++) { startS[i] = s; s += hist[i]; }
        startS[32] = s;
    }
    __syncthreads();
    if (t < 32) cursor[t] = startS[t];
    __syncthreads();

    for (int i = t; i < total; i += 256) {
        int2 e = ebuf[i];
        int p = atomicAdd(&cursor[e.x >> 17], 1);
        sorted[p] = e;
    }
    __syncthreads();

    const int group = t >> 4;          // 16 groups, each handles 2 nodes
    const int c4    = t & 15;          // channels [c4*4, c4*4+4)
    const int ovn   = min(*ov_cnt, OVCAP);

    for (int ln = group; ln < 32; ln += 16) {
        const int s0 = startS[ln];
        const int e0 = startS[ln + 1];
        float4 acc = make_float4(0.f, 0.f, 0.f, 0.f);

        int r = s0;
        for (; r + 4 <= e0; r += 4) {
            int2 q0 = sorted[r + 0];
            int2 q1 = sorted[r + 1];
            int2 q2 = sorted[r + 2];
            int2 q3 = sorted[r + 3];
            ushort4 v0 = *(const ushort4*)&hb[(size_t)(q0.x & 0x1FFFF) * N_OUT_C + c4 * 4];
            ushort4 v1 = *(const ushort4*)&hb[(size_t)(q1.x & 0x1FFFF) * N_OUT_C + c4 * 4];
            ushort4 v2 = *(const ushort4*)&hb[(size_t)(q2.x & 0x1FFFF) * N_OUT_C + c4 * 4];
            ushort4 v3 = *(const ushort4*)&hb[(size_t)(q3.x & 0x1FFFF) * N_OUT_C + c4 * 4];
            float w0 = __int_as_float(q0.y);
            float w1 = __int_as_float(q1.y);
            float w2 = __int_as_float(q2.y);
            float w3 = __int_as_float(q3.y);
            acc.x += w0 * bf2f(v0.x) + w1 * bf2f(v1.x) + w2 * bf2f(v2.x) + w3 * bf2f(v3.x);
            acc.y += w0 * bf2f(v0.y) + w1 * bf2f(v1.y) + w2 * bf2f(v2.y) + w3 * bf2f(v3.y);
            acc.z += w0 * bf2f(v0.z) + w1 * bf2f(v1.z) + w2 * bf2f(v2.z) + w3 * bf2f(v3.z);
            acc.w += w0 * bf2f(v0.w) + w1 * bf2f(v1.w) + w2 * bf2f(v2.w) + w3 * bf2f(v3.w);
        }
        for (; r < e0; r++) {
            int2 q = sorted[r];
            ushort4 v = *(const ushort4*)&hb[(size_t)(q.x & 0x1FFFF) * N_OUT_C + c4 * 4];
            float w = __int_as_float(q.y);
            acc.x += w * bf2f(v.x);
            acc.y += w * bf2f(v.y);
            acc.z += w * bf2f(v.z);
            acc.w += w * bf2f(v.w);
        }

        const int node = b * BKT_NODES + ln;
        if (ovn) {                      // ~never taken; correctness net
            for (int k = 0; k < ovn; k++) {
                int4 o = ov[k];
                if (o.x == node) {
                    ushort4 v = *(const ushort4*)&hb[(size_t)o.y * N_OUT_C + c4 * 4];
                    float w = __int_as_float(o.z);
                    acc.x += w * bf2f(v.x);
                    acc.y += w * bf2f(v.y);
                    acc.z += w * bf2f(v.z);
                    acc.w += w * bf2f(v.w);
                }
            }
        }

        // softmax over 64 channels = 16 lanes x 4
        float m = fmaxf(fmaxf(acc.x, acc.y), fmaxf(acc.z, acc.w));
        #pragma unroll
        for (int off = 1; off < 16; off <<= 1)
            m = fmaxf(m, __shfl_xor(m, off));

        float4 ev;
        ev.x = __expf(acc.x - m);
        ev.y = __expf(acc.y - m);
        ev.z = __expf(acc.z - m);
        ev.w = __expf(acc.w - m);

        float sum = ev.x + ev.y + ev.z + ev.w;
        #pragma unroll
        for (int off = 1; off < 16; off <<= 1)
            sum += __shfl_xor(sum, off);

        float inv = 1.0f / sum;
        *(float4*)&out[(size_t)node * N_OUT_C + c4 * 4] =
            make_float4(ev.x * inv, ev.y * inv, ev.z * inv, ev.w * inv);
    }
}

// ---------------------------------------------------------------------------
// Fallback path (ws too small): fp32 GEMM + atomic scatter + softmax
// ---------------------------------------------------------------------------
__global__ __launch_bounds__(256) void gemm_xw(const float* __restrict__ x,
                                               const float* __restrict__ W,
                                               float* __restrict__ h) {
    __shared__ float As[64][33];
    __shared__ float Bs[32][64];
    const int t  = threadIdx.x;
    const int tx = t & 15;
    const int ty = t >> 4;
    const int rowBase = blockIdx.x * 64;
    float acc[4][4] = {{0.f}};
    for (int k0 = 0; k0 < K_FEAT; k0 += 32) {
        #pragma unroll
        for (int i = 0; i < 2; i++) {
            int f = t + i * 256;
            int r = f >> 3, c4 = f & 7;
            int grow = rowBase + r;
            float4 v = make_float4(0.f, 0.f, 0.f, 0.f);
            if (grow < M_NODES)
                v = *(const float4*)&x[(size_t)grow * K_FEAT + k0 + c4 * 4];
            As[r][c4 * 4 + 0] = v.x; As[r][c4 * 4 + 1] = v.y;
            As[r][c4 * 4 + 2] = v.z; As[r][c4 * 4 + 3] = v.w;
        }
        #pragma unroll
        for (int i = 0; i < 2; i++) {
            int f = t + i * 256;
            ((float4*)Bs)[f] = ((const float4*)(W + (size_t)k0 * N_OUT_C))[f];
        }
        __syncthreads();
        #pragma unroll
        for (int k = 0; k < 32; k++) {
            float a0 = As[ty * 4 + 0][k], a1 = As[ty * 4 + 1][k];
            float a2 = As[ty * 4 + 2][k], a3 = As[ty * 4 + 3][k];
            float4 b = *(float4*)&Bs[k][tx * 4];
            acc[0][0] += a0 * b.x; acc[0][1] += a0 * b.y; acc[0][2] += a0 * b.z; acc[0][3] += a0 * b.w;
            acc[1][0] += a1 * b.x; acc[1][1] += a1 * b.y; acc[1][2] += a1 * b.z; acc[1][3] += a1 * b.w;
            acc[2][0] += a2 * b.x; acc[2][1] += a2 * b.y; acc[2][2] += a2 * b.z; acc[2][3] += a2 * b.w;
            acc[3][0] += a3 * b.x; acc[3][1] += a3 * b.y; acc[3][2] += a3 * b.z; acc[3][3] += a3 * b.w;
        }
        __syncthreads();
    }
    #pragma unroll
    for (int i = 0; i < 4; i++) {
        int row = rowBase + ty * 4 + i;
        if (row < M_NODES)
            *(float4*)&h[(size_t)row * N_OUT_C + tx * 4] =
                make_float4(acc[i][0], acc[i][1], acc[i][2], acc[i][3]);
    }
}

__global__ __launch_bounds__(256) void scatter_edges(const int* __restrict__ esrc,
                                                     const int* __restrict__ edst,
                                                     const float* __restrict__ ew,
                                                     const float* __restrict__ h,
                                                     float* __restrict__ agg) {
    int tid = blockIdx.x * 256 + threadIdx.x;
    int e = tid >> 4;
    int g = tid & 15;
    if (e >= N_EDGES_C) return;
    int s = esrc[e], d = edst[e];
    float w = ew[e];
    float4 v = *(const float4*)&h[(size_t)s * N_OUT_C + g * 4];
    float* p = agg + (size_t)d * N_OUT_C + g * 4;
    unsafeAtomicAdd(p + 0, v.x * w);
    unsafeAtomicAdd(p + 1, v.y * w);
    unsafeAtomicAdd(p + 2, v.z * w);
    unsafeAtomicAdd(p + 3, v.w * w);
}

__global__ __launch_bounds__(256) void softmax_rows(float* __restrict__ out) {
    int wave = (blockIdx.x * 256 + threadIdx.x) >> 6;
    int lane = threadIdx.x & 63;
    if (wave >= M_NODES) return;
    size_t idx = (size_t)wave * N_OUT_C + lane;
    float v = out[idx];
    float m = v;
    #pragma unroll
    for (int off = 32; off > 0; off >>= 1) m = fmaxf(m, __shfl_xor(m, off));
    float ev = __expf(v - m);
    float sum = ev;
    #pragma unroll
    for (int off = 32; off > 0; off >>= 1) sum += __shfl_xor(sum, off);
    out[idx] = ev / sum;
}

// ---------------------------------------------------------------------------
extern "C" void kernel_launch(void* const* d_in, const int* in_sizes, int n_in,
                              void* d_out, int out_size, void* d_ws, size_t ws_size,
                              hipStream_t stream) {
    const float* x    = (const float*)d_in[0];
    const int*   esrc = (const int*)d_in[1];
    const int*   edst = (const int*)d_in[2];
    const float* ew   = (const float*)d_in[3];
    const float* W    = (const float*)d_in[4];
    float* out = (float*)d_out;

    char* ws = (char*)d_ws;
    size_t off_hb    = 0;
    size_t sz_hb     = (size_t)M_NODES * N_OUT_C * sizeof(unsigned short);    // 12.8 MB
    size_t off_binc  = (off_hb + sz_hb + 15) & ~15ull;
    size_t sz_binc   = (size_t)NBIN * sizeof(int);                            // 392 B
    size_t off_ovc   = (off_binc + sz_binc + 15) & ~15ull;
    size_t sz_ovc    = 16;
    size_t off_bkc   = (off_ovc + sz_ovc + 15) & ~15ull;
    size_t sz_bkc    = (size_t)NB * sizeof(int);                              // 12.5 KB
    size_t off_binb  = (off_bkc + sz_bkc + 15) & ~15ull;
    size_t sz_binb   = (size_t)NBIN * BINCAP * sizeof(int2);                  // 14.45 MB
    size_t off_gbkt  = (off_binb + sz_binb + 15) & ~15ull;
    size_t sz_gbkt   = (size_t)NB * BKCAP * sizeof(int2);                     // 19.2 MB
    size_t off_wb    = (off_gbkt + sz_gbkt + 15) & ~15ull;
    size_t sz_wb     = (size_t)K_FEAT * N_OUT_C * sizeof(unsigned short);     // 64 KB
    size_t off_ov    = (off_wb + sz_wb + 15) & ~15ull;
    size_t sz_ov     = (size_t)OVCAP * sizeof(int4);                          // 128 KB
    size_t needed    = off_ov + sz_ov;                                        // ~46.7 MB

    if (ws_size >= needed) {
        unsigned short* hb  = (unsigned short*)(ws + off_hb);
        int*  bin_cnt = (int*)(ws + off_binc);
        int*  ov_cnt  = (int*)(ws + off_ovc);
        int*  bkcnt   = (int*)(ws + off_bkc);
        int2* binbuf  = (int2*)(ws + off_binb);
        int2* gbkt    = (int2*)(ws + off_gbkt);
        unsigned short* Wb = (unsigned short*)(ws + off_wb);
        int4* ov      = (int4*)(ws + off_ov);

        conv_w_zero<<<128, 256, 0, stream>>>(W, Wb, bin_cnt, ov_cnt);
        gemm_mfma<<<(M_NODES / 16 + 3) / 4, 256, 0, stream>>>(x, Wb, hb);
        bin_part<<<PA_BLOCKS, 256, 0, stream>>>(esrc, edst, ew, bin_cnt, binbuf, ov_cnt, ov);
        csr_build<<<NBIN, 256, 0, stream>>>(bin_cnt, binbuf, bkcnt, gbkt, ov_cnt, ov);
        bucket_agg<<<NB, 256, 0, stream>>>(bkcnt, gbkt, hb, ov_cnt, ov, out);
    } else {
        // fallback: fp32 gemm + atomic scatter
        float* h = (float*)ws;
        hipMemsetAsync(d_out, 0, (size_t)M_NODES * N_OUT_C * sizeof(float), stream);
        gemm_xw<<<(M_NODES + 63) / 64, 256, 0, stream>>>(x, W, h);
        scatter_edges<<<(N_EDGES_C * 16 + 255) / 256, 256, 0, stream>>>(esrc, edst, ew, h, out);
        softmax_rows<<<(M_NODES + 3) / 4, 256, 0, stream>>>(out);
    }
}

// Round 10
// 375.217 us; speedup vs baseline: 3.2025x; 1.0374x over previous
//
#include <hip/hip_runtime.h>
#include <hip/hip_bf16.h>
#include <string.h>

#define M_NODES 100000
#define K_FEAT 512
#define N_OUT_C 64
#define N_EDGES_C 1600000

// ---- two-phase partition geometry -----------------------------------------
#define NBIN 98                       // coarse bins: dst>>10 (1024 nodes/bin)
#define BINCAP 18432                  // mean 16384, +16 sigma
#define BKT_NODES 32                  // fine buckets: dst>>5
#define NB (M_NODES / BKT_NODES)      // 3125 buckets
#define BKCAP 768                     // mean 512, +11 sigma
#define OVCAP 8192                    // overflow net (expected 0 used)

#define PA_EPT 16
#define PA_TILE 4096                  // 256 threads * 16 edges
#define PA_BLOCKS ((N_EDGES_C + PA_TILE - 1) / PA_TILE)   // 391

#define CHUNKS 8                      // csr_build chunks per bin (784 blocks)
#define CHUNK_MAX ((BINCAP + CHUNKS - 1) / CHUNKS)        // 2304

// bin_cnt padded: one counter per 64B cache line (kills the 38K-atomics-on-
// 7-lines contention measured-by-inference in R9).
#define BINC_STRIDE 16

typedef __attribute__((ext_vector_type(8))) short short8;
typedef __attribute__((ext_vector_type(4))) float floatx4;

// fp32 -> bf16 round-to-nearest-even
static __device__ __forceinline__ unsigned short f2bf(float f) {
    unsigned int u = __float_as_uint(f);
    u += 0x7fffu + ((u >> 16) & 1u);
    return (unsigned short)(u >> 16);
}
static __device__ __forceinline__ float bf2f(unsigned short u) {
    return __uint_as_float((unsigned int)u << 16);
}
static __device__ __forceinline__ unsigned int cvt_pk_bf16(float lo, float hi) {
    __hip_bfloat162 h2 = __float22bfloat162_rn(make_float2(lo, hi));
    unsigned int u;
    memcpy(&u, &h2, sizeof(u));
    return u;
}

// ---------------------------------------------------------------------------
// conv_w_zero: W[512][64] fp32 -> Wb bf16 frag-swizzled; zero padded bin
// cursors, bucket cursors, ov_cnt.
// ---------------------------------------------------------------------------
__global__ __launch_bounds__(256) void conv_w_zero(const float* __restrict__ W,
                                                   unsigned short* __restrict__ Wb,
                                                   int* __restrict__ bin_cnt,
                                                   int* __restrict__ bkcnt,
                                                   int* __restrict__ ov_cnt) {
    int id = blockIdx.x * 256 + threadIdx.x;
    if (id < NBIN * BINC_STRIDE) bin_cnt[id] = 0;
    for (int i = id; i < NB; i += 32768) bkcnt[i] = 0;
    if (id == 0) *ov_cnt = 0;
    if (id < K_FEAT * N_OUT_C) {
        int k = id >> 6;
        int n = id & 63;
        Wb[((size_t)(k >> 3) * 64 + n) * 8 + (k & 7)] = f2bf(W[(size_t)k * 64 + n]);
    }
}

// ---------------------------------------------------------------------------
// MFMA GEMM: h[M,64] = x[M,512] @ W[512,64]. (Verified; unchanged.)
// ---------------------------------------------------------------------------
__global__ __launch_bounds__(256) void gemm_mfma(const float* __restrict__ x,
                                                 const unsigned short* __restrict__ Wb,
                                                 unsigned short* __restrict__ hb) {
    const int wid  = (blockIdx.x * 256 + (int)threadIdx.x) >> 6;
    const int lane = threadIdx.x & 63;
    if (wid >= M_NODES / 16) return;

    const int m    = lane & 15;
    const int quad = lane >> 4;
    const int rowBase = wid * 16;
    const float* aRow = x + (size_t)(rowBase + m) * K_FEAT + quad * 8;

    floatx4 acc0 = {0.f, 0.f, 0.f, 0.f};
    floatx4 acc1 = {0.f, 0.f, 0.f, 0.f};
    floatx4 acc2 = {0.f, 0.f, 0.f, 0.f};
    floatx4 acc3 = {0.f, 0.f, 0.f, 0.f};

    for (int k0 = 0; k0 < K_FEAT; k0 += 128) {
        float4 px[8];
        #pragma unroll
        for (int u = 0; u < 4; u++) {
            px[2 * u]     = *(const float4*)(aRow + k0 + u * 32);
            px[2 * u + 1] = *(const float4*)(aRow + k0 + u * 32 + 4);
        }
        #pragma unroll
        for (int u = 0; u < 4; u++) {
            const int kk = k0 + u * 32;
            union { short8 s; unsigned int uu[4]; } av;
            av.uu[0] = cvt_pk_bf16(px[2 * u].x,     px[2 * u].y);
            av.uu[1] = cvt_pk_bf16(px[2 * u].z,     px[2 * u].w);
            av.uu[2] = cvt_pk_bf16(px[2 * u + 1].x, px[2 * u + 1].y);
            av.uu[3] = cvt_pk_bf16(px[2 * u + 1].z, px[2 * u + 1].w);
            short8 a = av.s;

            const unsigned short* wbase = Wb + (size_t)((kk >> 3) + quad) * 512 + m * 8;
            short8 b0 = *(const short8*)(wbase + 0 * 128);
            short8 b1 = *(const short8*)(wbase + 1 * 128);
            short8 b2 = *(const short8*)(wbase + 2 * 128);
            short8 b3 = *(const short8*)(wbase + 3 * 128);

            acc0 = __builtin_amdgcn_mfma_f32_16x16x32_bf16(a, b0, acc0, 0, 0, 0);
            acc1 = __builtin_amdgcn_mfma_f32_16x16x32_bf16(a, b1, acc1, 0, 0, 0);
            acc2 = __builtin_amdgcn_mfma_f32_16x16x32_bf16(a, b2, acc2, 0, 0, 0);
            acc3 = __builtin_amdgcn_mfma_f32_16x16x32_bf16(a, b3, acc3, 0, 0, 0);
        }
    }

    unsigned short* hp = hb + (size_t)(rowBase + quad * 4) * N_OUT_C + m;
    #pragma unroll
    for (int r = 0; r < 4; r++) {
        hp[(size_t)r * N_OUT_C + 0]  = f2bf(acc0[r]);
        hp[(size_t)r * N_OUT_C + 16] = f2bf(acc1[r]);
        hp[(size_t)r * N_OUT_C + 32] = f2bf(acc2[r]);
        hp[(size_t)r * N_OUT_C + 48] = f2bf(acc3[r]);
    }
}

// ---------------------------------------------------------------------------
// bin_part (phase A): partition edges into 98 coarse bins (dst>>10).
// LDS histogram -> ONE padded-line global atomic per bin per block (range
// reservation, now contention-free) -> per-edge LDS-cursor scatter.
// Entry: int2( src | (dst&1023)<<17 , weight_bits ).
// ---------------------------------------------------------------------------
__global__ __launch_bounds__(256) void bin_part(const int* __restrict__ esrc,
                                                const int* __restrict__ edst,
                                                const float* __restrict__ ew,
                                                int* __restrict__ bin_cnt,
                                                int2* __restrict__ binbuf,
                                                int* __restrict__ ov_cnt,
                                                int4* __restrict__ ov) {
    __shared__ int hist[NBIN];
    __shared__ int cur[NBIN];
    const int t    = threadIdx.x;
    const int tile = blockIdx.x * PA_TILE;

    int ss[PA_EPT], dd[PA_EPT];
    float wwv[PA_EPT];
    #pragma unroll
    for (int j = 0; j < PA_EPT / 4; j++) {
        int idx = tile + j * 1024 + t * 4;
        if (idx < N_EDGES_C) {
            int4   s = *(const int4*)&esrc[idx];
            int4   d = *(const int4*)&edst[idx];
            float4 w = *(const float4*)&ew[idx];
            ss[4*j+0] = s.x; ss[4*j+1] = s.y; ss[4*j+2] = s.z; ss[4*j+3] = s.w;
            dd[4*j+0] = d.x; dd[4*j+1] = d.y; dd[4*j+2] = d.z; dd[4*j+3] = d.w;
            wwv[4*j+0] = w.x; wwv[4*j+1] = w.y; wwv[4*j+2] = w.z; wwv[4*j+3] = w.w;
        } else {
            dd[4*j+0] = dd[4*j+1] = dd[4*j+2] = dd[4*j+3] = -1;
            ss[4*j+0] = ss[4*j+1] = ss[4*j+2] = ss[4*j+3] = 0;
            wwv[4*j+0] = wwv[4*j+1] = wwv[4*j+2] = wwv[4*j+3] = 0.f;
        }
    }

    if (t < NBIN) hist[t] = 0;
    __syncthreads();

    #pragma unroll
    for (int i = 0; i < PA_EPT; i++)
        if (dd[i] >= 0) atomicAdd(&hist[dd[i] >> 10], 1);
    __syncthreads();

    if (t < NBIN) cur[t] = atomicAdd(&bin_cnt[t * BINC_STRIDE], hist[t]);
    __syncthreads();

    #pragma unroll
    for (int i = 0; i < PA_EPT; i++) {
        if (dd[i] < 0) continue;
        int b = dd[i] >> 10;
        int p = atomicAdd(&cur[b], 1);                        // LDS cursor
        if (p < BINCAP) {
            binbuf[(size_t)b * BINCAP + p] =
                make_int2(ss[i] | ((dd[i] & 1023) << 17), __float_as_int(wwv[i]));
        } else {
            int k = atomicAdd(ov_cnt, 1);
            if (k < OVCAP) ov[k] = make_int4(dd[i], ss[i], __float_as_int(wwv[i]), 0);
        }
    }
}

// ---------------------------------------------------------------------------
// csr_build (phase B): 8 chunks per bin = 784 blocks (was 98 -- no-TLP
// latency exposure fixed). Each chunk stages <=2304 entries in LDS,
// histograms 32 buckets, reserves contiguous ranges in gbkt via one global
// atomic per bucket, scatters in ~512B bursts.
// Bucket entry: int2( src | (dst&31)<<17 , weight_bits ).
// ---------------------------------------------------------------------------
__global__ __launch_bounds__(256) void csr_build(const int* __restrict__ bin_cnt,
                                                 const int2* __restrict__ binbuf,
                                                 int* __restrict__ bkcnt,
                                                 int2* __restrict__ gbkt,
                                                 int* __restrict__ ov_cnt,
                                                 int4* __restrict__ ov) {
    __shared__ int2 stage[CHUNK_MAX];   // 18.4 KB
    __shared__ int  hist[32];
    __shared__ int  baseS[32];
    __shared__ int  cur[32];

    const int bin   = blockIdx.x >> 3;
    const int chunk = blockIdx.x & (CHUNKS - 1);
    const int t     = threadIdx.x;

    const int cntb = min(bin_cnt[bin * BINC_STRIDE], BINCAP);
    const int csz  = (cntb + CHUNKS - 1) / CHUNKS;
    const int lo   = chunk * csz;
    const int hi   = min(lo + csz, cntb);
    const int n    = hi - lo;                    // <= CHUNK_MAX

    if (t < 32) hist[t] = 0;
    __syncthreads();

    const int2* src = binbuf + (size_t)bin * BINCAP + lo;
    for (int i = t; i < n; i += 256) {
        int2 e = src[i];
        stage[i] = e;
        atomicAdd(&hist[((e.x >> 17) & 1023) >> 5], 1);
    }
    __syncthreads();

    if (t < 32) {
        int gb = (bin << 5) + t;
        baseS[t] = (gb < NB && hist[t] > 0) ? atomicAdd(&bkcnt[gb], hist[t]) : 0;
        cur[t] = 0;
    }
    __syncthreads();

    for (int i = t; i < n; i += 256) {
        int2 e = stage[i];
        int ld = (e.x >> 17) & 1023;
        int bl = ld >> 5;
        int p  = baseS[bl] + atomicAdd(&cur[bl], 1);
        if (p < BKCAP) {
            gbkt[(size_t)((bin << 5) + bl) * BKCAP + p] =
                make_int2((e.x & 0x1FFFF) | ((ld & 31) << 17), e.y);
        } else {
            int k = atomicAdd(ov_cnt, 1);
            if (k < OVCAP) ov[k] = make_int4((bin << 10) + ld, e.x & 0x1FFFF, e.y, 0);
        }
    }
}

// ---------------------------------------------------------------------------
// bucket_agg: one block per 32-node bucket. LDS counting sort + register
// gather + softmax. (Verified core; unchanged.)
// ---------------------------------------------------------------------------
__global__ __launch_bounds__(256) void bucket_agg(const int* __restrict__ bkcnt,
                                                  const int2* __restrict__ gbkt,
                                                  const unsigned short* __restrict__ hb,
                                                  const int* __restrict__ ov_cnt,
                                                  const int4* __restrict__ ov,
                                                  float* __restrict__ out) {
    __shared__ int2 ebuf[BKCAP];     // 6 KB
    __shared__ int2 sorted[BKCAP];   // 6 KB
    __shared__ int  hist[32];
    __shared__ int  startS[33];
    __shared__ int  cursor[32];

    const int b = blockIdx.x;
    const int t = threadIdx.x;

    const int total = min(bkcnt[b], BKCAP);
    if (t < 32) hist[t] = 0;
    __syncthreads();

    const int2* g = gbkt + (size_t)b * BKCAP;
    for (int i = t; i < total; i += 256) ebuf[i] = g[i];
    __syncthreads();

    for (int i = t; i < total; i += 256) atomicAdd(&hist[ebuf[i].x >> 17], 1);
    __syncthreads();

    if (t == 0) {
        int s = 0;
        #pragma unroll
        for (int i = 0; i < 32; i++) { startS[i] = s; s += hist[i]; }
        startS[32] = s;
    }
    __syncthreads();
    if (t < 32) cursor[t] = startS[t];
    __syncthreads();

    for (int i = t; i < total; i += 256) {
        int2 e = ebuf[i];
        int p = atomicAdd(&cursor[e.x >> 17], 1);
        sorted[p] = e;
    }
    __syncthreads();

    const int group = t >> 4;          // 16 groups, each handles 2 nodes
    const int c4    = t & 15;          // channels [c4*4, c4*4+4)
    const int ovn   = min(*ov_cnt, OVCAP);

    for (int ln = group; ln < 32; ln += 16) {
        const int s0 = startS[ln];
        const int e0 = startS[ln + 1];
        float4 acc = make_float4(0.f, 0.f, 0.f, 0.f);

        int r = s0;
        for (; r + 4 <= e0; r += 4) {
            int2 q0 = sorted[r + 0];
            int2 q1 = sorted[r + 1];
            int2 q2 = sorted[r + 2];
            int2 q3 = sorted[r + 3];
            ushort4 v0 = *(const ushort4*)&hb[(size_t)(q0.x & 0x1FFFF) * N_OUT_C + c4 * 4];
            ushort4 v1 = *(const ushort4*)&hb[(size_t)(q1.x & 0x1FFFF) * N_OUT_C + c4 * 4];
            ushort4 v2 = *(const ushort4*)&hb[(size_t)(q2.x & 0x1FFFF) * N_OUT_C + c4 * 4];
            ushort4 v3 = *(const ushort4*)&hb[(size_t)(q3.x & 0x1FFFF) * N_OUT_C + c4 * 4];
            float w0 = __int_as_float(q0.y);
            float w1 = __int_as_float(q1.y);
            float w2 = __int_as_float(q2.y);
            float w3 = __int_as_float(q3.y);
            acc.x += w0 * bf2f(v0.x) + w1 * bf2f(v1.x) + w2 * bf2f(v2.x) + w3 * bf2f(v3.x);
            acc.y += w0 * bf2f(v0.y) + w1 * bf2f(v1.y) + w2 * bf2f(v2.y) + w3 * bf2f(v3.y);
            acc.z += w0 * bf2f(v0.z) + w1 * bf2f(v1.z) + w2 * bf2f(v2.z) + w3 * bf2f(v3.z);
            acc.w += w0 * bf2f(v0.w) + w1 * bf2f(v1.w) + w2 * bf2f(v2.w) + w3 * bf2f(v3.w);
        }
        for (; r < e0; r++) {
            int2 q = sorted[r];
            ushort4 v = *(const ushort4*)&hb[(size_t)(q.x & 0x1FFFF) * N_OUT_C + c4 * 4];
            float w = __int_as_float(q.y);
            acc.x += w * bf2f(v.x);
            acc.y += w * bf2f(v.y);
            acc.z += w * bf2f(v.z);
            acc.w += w * bf2f(v.w);
        }

        const int node = b * BKT_NODES + ln;
        if (ovn) {                      // ~never taken; correctness net
            for (int k = 0; k < ovn; k++) {
                int4 o = ov[k];
                if (o.x == node) {
                    ushort4 v = *(const ushort4*)&hb[(size_t)o.y * N_OUT_C + c4 * 4];
                    float w = __int_as_float(o.z);
                    acc.x += w * bf2f(v.x);
                    acc.y += w * bf2f(v.y);
                    acc.z += w * bf2f(v.z);
                    acc.w += w * bf2f(v.w);
                }
            }
        }

        // softmax over 64 channels = 16 lanes x 4
        float m = fmaxf(fmaxf(acc.x, acc.y), fmaxf(acc.z, acc.w));
        #pragma unroll
        for (int off = 1; off < 16; off <<= 1)
            m = fmaxf(m, __shfl_xor(m, off));

        float4 ev;
        ev.x = __expf(acc.x - m);
        ev.y = __expf(acc.y - m);
        ev.z = __expf(acc.z - m);
        ev.w = __expf(acc.w - m);

        float sum = ev.x + ev.y + ev.z + ev.w;
        #pragma unroll
        for (int off = 1; off < 16; off <<= 1)
            sum += __shfl_xor(sum, off);

        float inv = 1.0f / sum;
        *(float4*)&out[(size_t)node * N_OUT_C + c4 * 4] =
            make_float4(ev.x * inv, ev.y * inv, ev.z * inv, ev.w * inv);
    }
}

// ---------------------------------------------------------------------------
// Fallback path (ws too small): fp32 GEMM + atomic scatter + softmax
// ---------------------------------------------------------------------------
__global__ __launch_bounds__(256) void gemm_xw(const float* __restrict__ x,
                                               const float* __restrict__ W,
                                               float* __restrict__ h) {
    __shared__ float As[64][33];
    __shared__ float Bs[32][64];
    const int t  = threadIdx.x;
    const int tx = t & 15;
    const int ty = t >> 4;
    const int rowBase = blockIdx.x * 64;
    float acc[4][4] = {{0.f}};
    for (int k0 = 0; k0 < K_FEAT; k0 += 32) {
        #pragma unroll
        for (int i = 0; i < 2; i++) {
            int f = t + i * 256;
            int r = f >> 3, c4 = f & 7;
            int grow = rowBase + r;
            float4 v = make_float4(0.f, 0.f, 0.f, 0.f);
            if (grow < M_NODES)
                v = *(const float4*)&x[(size_t)grow * K_FEAT + k0 + c4 * 4];
            As[r][c4 * 4 + 0] = v.x; As[r][c4 * 4 + 1] = v.y;
            As[r][c4 * 4 + 2] = v.z; As[r][c4 * 4 + 3] = v.w;
        }
        #pragma unroll
        for (int i = 0; i < 2; i++) {
            int f = t + i * 256;
            ((float4*)Bs)[f] = ((const float4*)(W + (size_t)k0 * N_OUT_C))[f];
        }
        __syncthreads();
        #pragma unroll
        for (int k = 0; k < 32; k++) {
            float a0 = As[ty * 4 + 0][k], a1 = As[ty * 4 + 1][k];
            float a2 = As[ty * 4 + 2][k], a3 = As[ty * 4 + 3][k];
            float4 b = *(float4*)&Bs[k][tx * 4];
            acc[0][0] += a0 * b.x; acc[0][1] += a0 * b.y; acc[0][2] += a0 * b.z; acc[0][3] += a0 * b.w;
            acc[1][0] += a1 * b.x; acc[1][1] += a1 * b.y; acc[1][2] += a1 * b.z; acc[1][3] += a1 * b.w;
            acc[2][0] += a2 * b.x; acc[2][1] += a2 * b.y; acc[2][2] += a2 * b.z; acc[2][3] += a2 * b.w;
            acc[3][0] += a3 * b.x; acc[3][1] += a3 * b.y; acc[3][2] += a3 * b.z; acc[3][3] += a3 * b.w;
        }
        __syncthreads();
    }
    #pragma unroll
    for (int i = 0; i < 4; i++) {
        int row = rowBase + ty * 4 + i;
        if (row < M_NODES)
            *(float4*)&h[(size_t)row * N_OUT_C + tx * 4] =
                make_float4(acc[i][0], acc[i][1], acc[i][2], acc[i][3]);
    }
}

__global__ __launch_bounds__(256) void scatter_edges(const int* __restrict__ esrc,
                                                     const int* __restrict__ edst,
                                                     const float* __restrict__ ew,
                                                     const float* __restrict__ h,
                                                     float* __restrict__ agg) {
    int tid = blockIdx.x * 256 + threadIdx.x;
    int e = tid >> 4;
    int g = tid & 15;
    if (e >= N_EDGES_C) return;
    int s = esrc[e], d = edst[e];
    float w = ew[e];
    float4 v = *(const float4*)&h[(size_t)s * N_OUT_C + g * 4];
    float* p = agg + (size_t)d * N_OUT_C + g * 4;
    unsafeAtomicAdd(p + 0, v.x * w);
    unsafeAtomicAdd(p + 1, v.y * w);
    unsafeAtomicAdd(p + 2, v.z * w);
    unsafeAtomicAdd(p + 3, v.w * w);
}

__global__ __launch_bounds__(256) void softmax_rows(float* __restrict__ out) {
    int wave = (blockIdx.x * 256 + threadIdx.x) >> 6;
    int lane = threadIdx.x & 63;
    if (wave >= M_NODES) return;
    size_t idx = (size_t)wave * N_OUT_C + lane;
    float v = out[idx];
    float m = v;
    #pragma unroll
    for (int off = 32; off > 0; off >>= 1) m = fmaxf(m, __shfl_xor(m, off));
    float ev = __expf(v - m);
    float sum = ev;
    #pragma unroll
    for (int off = 32; off > 0; off >>= 1) sum += __shfl_xor(sum, off);
    out[idx] = ev / sum;
}

// ---------------------------------------------------------------------------
extern "C" void kernel_launch(void* const* d_in, const int* in_sizes, int n_in,
                              void* d_out, int out_size, void* d_ws, size_t ws_size,
                              hipStream_t stream) {
    const float* x    = (const float*)d_in[0];
    const int*   esrc = (const int*)d_in[1];
    const int*   edst = (const int*)d_in[2];
    const float* ew   = (const float*)d_in[3];
    const float* W    = (const float*)d_in[4];
    float* out = (float*)d_out;

    char* ws = (char*)d_ws;
    size_t off_hb    = 0;
    size_t sz_hb     = (size_t)M_NODES * N_OUT_C * sizeof(unsigned short);    // 12.8 MB
    size_t off_binc  = (off_hb + sz_hb + 63) & ~63ull;
    size_t sz_binc   = (size_t)NBIN * BINC_STRIDE * sizeof(int);              // 6.3 KB (line-padded)
    size_t off_ovc   = (off_binc + sz_binc + 63) & ~63ull;
    size_t sz_ovc    = 64;
    size_t off_bkc   = (off_ovc + sz_ovc + 63) & ~63ull;
    size_t sz_bkc    = (size_t)NB * sizeof(int);                              // 12.5 KB
    size_t off_binb  = (off_bkc + sz_bkc + 15) & ~15ull;
    size_t sz_binb   = (size_t)NBIN * BINCAP * sizeof(int2);                  // 14.45 MB
    size_t off_gbkt  = (off_binb + sz_binb + 15) & ~15ull;
    size_t sz_gbkt   = (size_t)NB * BKCAP * sizeof(int2);                     // 19.2 MB
    size_t off_wb    = (off_gbkt + sz_gbkt + 15) & ~15ull;
    size_t sz_wb     = (size_t)K_FEAT * N_OUT_C * sizeof(unsigned short);     // 64 KB
    size_t off_ov    = (off_wb + sz_wb + 15) & ~15ull;
    size_t sz_ov     = (size_t)OVCAP * sizeof(int4);                          // 128 KB
    size_t needed    = off_ov + sz_ov;                                        // ~46.7 MB

    if (ws_size >= needed) {
        unsigned short* hb  = (unsigned short*)(ws + off_hb);
        int*  bin_cnt = (int*)(ws + off_binc);
        int*  ov_cnt  = (int*)(ws + off_ovc);
        int*  bkcnt   = (int*)(ws + off_bkc);
        int2* binbuf  = (int2*)(ws + off_binb);
        int2* gbkt    = (int2*)(ws + off_gbkt);
        unsigned short* Wb = (unsigned short*)(ws + off_wb);
        int4* ov      = (int4*)(ws + off_ov);

        conv_w_zero<<<128, 256, 0, stream>>>(W, Wb, bin_cnt, bkcnt, ov_cnt);
        gemm_mfma<<<(M_NODES / 16 + 3) / 4, 256, 0, stream>>>(x, Wb, hb);
        bin_part<<<PA_BLOCKS, 256, 0, stream>>>(esrc, edst, ew, bin_cnt, binbuf, ov_cnt, ov);
        csr_build<<<NBIN * CHUNKS, 256, 0, stream>>>(bin_cnt, binbuf, bkcnt, gbkt, ov_cnt, ov);
        bucket_agg<<<NB, 256, 0, stream>>>(bkcnt, gbkt, hb, ov_cnt, ov, out);
    } else {
        // fallback: fp32 gemm + atomic scatter
        float* h = (float*)ws;
        hipMemsetAsync(d_out, 0, (size_t)M_NODES * N_OUT_C * sizeof(float), stream);
        gemm_xw<<<(M_NODES + 63) / 64, 256, 0, stream>>>(x, W, h);
        scatter_edges<<<(N_EDGES_C * 16 + 255) / 256, 256, 0, stream>>>(esrc, edst, ew, h, out);
        softmax_rows<<<(M_NODES + 3) / 4, 256, 0, stream>>>(out);
    }
}